// Round 2
// baseline (234.410 us; speedup 1.0000x reference)
//
#include <hip/hip_runtime.h>

// Head: causal MHA, B=128 T=256 C=384 H=6 d=64. Inputs fp32, output fp32.
// MFMA path: convert to bf16 (fp32 accum). wtrans -> gemm_qkv -> attn.

typedef unsigned short u16;
typedef float f32x4 __attribute__((ext_vector_type(4)));
typedef short s16x8 __attribute__((ext_vector_type(8)));

static constexpr int BB = 128;
static constexpr int TT = 256;
static constexpr int CC = 384;
static constexpr int HH = 6;
static constexpr int DD = 64;
static constexpr int MM = BB * TT;  // 32768

// ws layout in bf16 elements: Q, K, V [M,C] then 3x WT [C,C]
static constexpr size_t QOFF  = 0;
static constexpr size_t KOFF  = (size_t)MM * CC;
static constexpr size_t VOFF  = (size_t)2 * MM * CC;
static constexpr size_t WTOFF = (size_t)3 * MM * CC;

__device__ __forceinline__ u16 f2bf(float f) {
  unsigned u = __float_as_uint(f);
  u += 0x7fffu + ((u >> 16) & 1u);   // RTN-even
  return (u16)(u >> 16);
}

// ---------- W transpose + fp32->bf16: WT[n][k] = bf16(W[k][n]) ----------
__global__ void wtrans(const float* __restrict__ Wq, const float* __restrict__ Wk,
                       const float* __restrict__ Wv, u16* __restrict__ ws) {
  const float* W = (blockIdx.y == 0) ? Wq : (blockIdx.y == 1) ? Wk : Wv;
  u16* WT = ws + WTOFF + (size_t)blockIdx.y * CC * CC;
  int i = blockIdx.x * 256 + threadIdx.x;  // coalesced fp32 read
  int k = i / CC, n = i % CC;
  WT[(size_t)n * CC + k] = f2bf(W[i]);
}

// ---------- QKV projection: Y = X @ W (A: fp32 [M,384] -> bf16 LDS; B^T = WT bf16) ----------
// 128x128 tile, BK=64, 4 waves each 64x64 (4x4 of 16x16x32 MFMA).
__global__ __launch_bounds__(256) void gemm_qkv(const float* __restrict__ X,
                                                u16* __restrict__ ws) {
  const u16* WT = ws + WTOFF + (size_t)blockIdx.z * CC * CC;
  u16* Y = ws + (size_t)blockIdx.z * MM * CC;

  __shared__ u16 As[128][72];  // +8 pad: 2-way bank alias only (free)
  __shared__ u16 Bs[128][72];

  const int tid = threadIdx.x;
  const int lane = tid & 63;
  const int w = tid >> 6;
  const int quad = lane >> 4;
  const int col = lane & 15;
  const int m0 = blockIdx.x * 128;
  const int n0 = blockIdx.y * 128;
  const int wm = (w >> 1) * 64;
  const int wn = (w & 1) * 64;

  f32x4 acc[4][4] = {};

  for (int kt = 0; kt < 6; ++kt) {
    if (kt) __syncthreads();
#pragma unroll
    for (int i = 0; i < 4; ++i) {
      int c = i * 256 + tid;
      int row = c >> 3, c8 = (c & 7) * 8;
      // A: fp32 -> bf16 convert in flight
      f32x4 a0 = *(const f32x4*)(X + (size_t)(m0 + row) * CC + kt * 64 + c8);
      f32x4 a1 = *(const f32x4*)(X + (size_t)(m0 + row) * CC + kt * 64 + c8 + 4);
      s16x8 ab;
#pragma unroll
      for (int j = 0; j < 4; ++j) { ab[j] = (short)f2bf(a0[j]); ab[4 + j] = (short)f2bf(a1[j]); }
      *(s16x8*)(&As[row][c8]) = ab;
      *(uint4*)(&Bs[row][c8]) =
          *(const uint4*)(WT + (size_t)(n0 + row) * CC + kt * 64 + c8);
    }
    __syncthreads();

    s16x8 af[4][2], bf[4][2];
#pragma unroll
    for (int mt = 0; mt < 4; ++mt)
#pragma unroll
      for (int ks = 0; ks < 2; ++ks)
        af[mt][ks] = *(const s16x8*)(&As[wm + mt * 16 + col][ks * 32 + quad * 8]);
#pragma unroll
    for (int nt = 0; nt < 4; ++nt)
#pragma unroll
      for (int ks = 0; ks < 2; ++ks)
        bf[nt][ks] = *(const s16x8*)(&Bs[wn + nt * 16 + col][ks * 32 + quad * 8]);

#pragma unroll
    for (int ks = 0; ks < 2; ++ks)
#pragma unroll
      for (int mt = 0; mt < 4; ++mt)
#pragma unroll
        for (int nt = 0; nt < 4; ++nt)
          acc[mt][nt] = __builtin_amdgcn_mfma_f32_16x16x32_bf16(
              af[mt][ks], bf[nt][ks], acc[mt][nt], 0, 0, 0);
  }

  // C/D layout: col = lane&15, row = quad*4 + r (m89-verified)
#pragma unroll
  for (int mt = 0; mt < 4; ++mt)
#pragma unroll
    for (int nt = 0; nt < 4; ++nt) {
      int mg = m0 + wm + mt * 16 + quad * 4;
      int ng = n0 + wn + nt * 16 + col;
#pragma unroll
      for (int r = 0; r < 4; ++r)
        Y[(size_t)(mg + r) * CC + ng] = f2bf(acc[mt][nt][r]);
    }
}

// ---------- Flash attention: one block per (b,h), wave w owns query rows [64w,64w+64) ----------
__global__ __launch_bounds__(256) void attn(const u16* __restrict__ ws,
                                            float* __restrict__ out) {
  const u16* Qg = ws + QOFF;
  const u16* Kg = ws + KOFF;
  const u16* Vg = ws + VOFF;

  const int b = blockIdx.x / HH;
  const int h = blockIdx.x % HH;

  __shared__ u16 Ks[TT][72];       // all 256 keys resident, [key][d]
  __shared__ u16 Vt[DD][72];       // per-key-tile, transposed [d][key_local]
  __shared__ u16 Ps[4][16][72];    // per-wave P round-trip (C/D -> A-operand)

  const int tid = threadIdx.x;
  const int lane = tid & 63;
  const int w = tid >> 6;
  const int quad = lane >> 4;
  const int col = lane & 15;

  // stage K: 256 rows x 64 d
#pragma unroll
  for (int i = 0; i < 8; ++i) {
    int c = i * 256 + tid;
    int row = c >> 3, c8 = (c & 7) * 8;
    *(uint4*)(&Ks[row][c8]) =
        *(const uint4*)(Kg + (size_t)(b * TT + row) * CC + h * DD + c8);
  }

  // preload Q fragments (A-operand: m=lane&15, k=quad*8+j)
  s16x8 qf[4][2];
#pragma unroll
  for (int mt = 0; mt < 4; ++mt)
#pragma unroll
    for (int ks = 0; ks < 2; ++ks)
      qf[mt][ks] = *(const s16x8*)(Qg + (size_t)(b * TT + w * 64 + mt * 16 + col) * CC +
                                   h * DD + ks * 32 + quad * 8);

  __syncthreads();

  f32x4 o[4][4] = {};
  float mst[4][4], lst[4][4];
#pragma unroll
  for (int mt = 0; mt < 4; ++mt)
#pragma unroll
    for (int r = 0; r < 4; ++r) { mst[mt][r] = -3.0e38f; lst[mt][r] = 0.0f; }

  // logits in base-2 units: u = S_raw * (1/sqrt(384)) * log2(e)
  const float csc = 0.051031036307982884f * 1.4426950408889634f;

  for (int kt = 0; kt < 4; ++kt) {
    __syncthreads();  // prev iter's Vt reads done before overwrite
    // stage V tile kt transposed: Vt[d][key_local]
#pragma unroll
    for (int i = 0; i < 2; ++i) {
      int c = i * 256 + tid;
      int row = c >> 3, c8 = (c & 7) * 8;
      s16x8 v = *(const s16x8*)(Vg + (size_t)(b * TT + kt * 64 + row) * CC + h * DD + c8);
#pragma unroll
      for (int j = 0; j < 8; ++j) Vt[c8 + j][row] = (u16)v[j];
    }
    __syncthreads();

    if (w >= kt) {
      // B-operand frags: lane holds B[k=quad*8+j][n=lane&15]
      s16x8 kf[4][2], vf[4][2];
#pragma unroll
      for (int nt = 0; nt < 4; ++nt)
#pragma unroll
        for (int ks = 0; ks < 2; ++ks) {
          kf[nt][ks] = *(const s16x8*)(&Ks[kt * 64 + nt * 16 + col][ks * 32 + quad * 8]);
          vf[nt][ks] = *(const s16x8*)(&Vt[nt * 16 + col][ks * 32 + quad * 8]);
        }

#pragma unroll
      for (int mt = 0; mt < 4; ++mt) {
        // S = Q K^T (64 q-rows of this mt x 64 keys)
        f32x4 s[4] = {};
#pragma unroll
        for (int ks = 0; ks < 2; ++ks)
#pragma unroll
          for (int nt = 0; nt < 4; ++nt)
            s[nt] = __builtin_amdgcn_mfma_f32_16x16x32_bf16(qf[mt][ks], kf[nt][ks],
                                                            s[nt], 0, 0, 0);
        // scale + causal mask (diagonal tile only), row max over 16 lanes of quad
        float rmax[4] = {-3.0e38f, -3.0e38f, -3.0e38f, -3.0e38f};
#pragma unroll
        for (int nt = 0; nt < 4; ++nt)
#pragma unroll
          for (int r = 0; r < 4; ++r) {
            float t = s[nt][r] * csc;
            if (kt == w && (nt * 16 + col) > (mt * 16 + quad * 4 + r)) t = -3.0e38f;
            s[nt][r] = t;
            rmax[r] = fmaxf(rmax[r], t);
          }
#pragma unroll
        for (int r = 0; r < 4; ++r) {
          rmax[r] = fmaxf(rmax[r], __shfl_xor(rmax[r], 1));
          rmax[r] = fmaxf(rmax[r], __shfl_xor(rmax[r], 2));
          rmax[r] = fmaxf(rmax[r], __shfl_xor(rmax[r], 4));
          rmax[r] = fmaxf(rmax[r], __shfl_xor(rmax[r], 8));
        }
        float alpha[4];
#pragma unroll
        for (int r = 0; r < 4; ++r) {
          float mn = fmaxf(mst[mt][r], rmax[r]);
          alpha[r] = exp2f(mst[mt][r] - mn);
          mst[mt][r] = mn;
          lst[mt][r] *= alpha[r];
        }
        // P = exp2(u - m), per-lane partial l; P -> LDS as bf16
#pragma unroll
        for (int nt = 0; nt < 4; ++nt)
#pragma unroll
          for (int r = 0; r < 4; ++r) {
            float p = exp2f(s[nt][r] - mst[mt][r]);
            lst[mt][r] += p;
            Ps[w][quad * 4 + r][nt * 16 + col] = f2bf(p);
          }
        // rescale O rows of this mt
#pragma unroll
        for (int nt = 0; nt < 4; ++nt)
#pragma unroll
          for (int r = 0; r < 4; ++r) o[mt][nt][r] *= alpha[r];

        // wave-local visibility of Ps writes (no block barrier: waves diverge in kt)
        asm volatile("s_waitcnt lgkmcnt(0)" ::: "memory");

        s16x8 pf[2];
#pragma unroll
        for (int ks = 0; ks < 2; ++ks)
          pf[ks] = *(const s16x8*)(&Ps[w][col][ks * 32 + quad * 8]);
#pragma unroll
        for (int ks = 0; ks < 2; ++ks)
#pragma unroll
          for (int nt = 0; nt < 4; ++nt)
            o[mt][nt] = __builtin_amdgcn_mfma_f32_16x16x32_bf16(pf[ks], vf[nt][ks],
                                                                o[mt][nt], 0, 0, 0);
      }
    }
  }

  // epilogue: l row-reduce, normalize, fp32 store
#pragma unroll
  for (int mt = 0; mt < 4; ++mt) {
    float inv[4];
#pragma unroll
    for (int r = 0; r < 4; ++r) {
      float ls = lst[mt][r];
      ls += __shfl_xor(ls, 1);
      ls += __shfl_xor(ls, 2);
      ls += __shfl_xor(ls, 4);
      ls += __shfl_xor(ls, 8);
      inv[r] = 1.0f / ls;
    }
#pragma unroll
    for (int nt = 0; nt < 4; ++nt) {
      int qg = b * TT + w * 64 + mt * 16 + quad * 4;
      int dg = h * DD + nt * 16 + col;
#pragma unroll
      for (int r = 0; r < 4; ++r)
        out[(size_t)(qg + r) * CC + dg] = o[mt][nt][r] * inv[r];
    }
  }
}

extern "C" void kernel_launch(void* const* d_in, const int* in_sizes, int n_in,
                              void* d_out, int out_size, void* d_ws, size_t ws_size,
                              hipStream_t stream) {
  const float* x  = (const float*)d_in[0];
  const float* wq = (const float*)d_in[1];
  const float* wk = (const float*)d_in[2];
  const float* wv = (const float*)d_in[3];
  u16* ws  = (u16*)d_ws;
  float* out = (float*)d_out;

  wtrans<<<dim3(CC * CC / 256, 3), 256, 0, stream>>>(wq, wk, wv, ws);
  gemm_qkv<<<dim3(MM / 128, CC / 128, 3), 256, 0, stream>>>(x, ws);
  attn<<<dim3(BB * HH), 256, 0, stream>>>(ws, out);
}

// Round 3
// 229.390 us; speedup vs baseline: 1.0219x; 1.0219x over previous
//
#include <hip/hip_runtime.h>

// Head: causal MHA, B=128 T=256 C=384 H=6 d=64. Inputs fp32, output fp32.
// wtrans (W->W^T bf16, Wq pre-scaled) -> gemm_qkv (Q,K row-major; V^T) -> attn
// attn: 1 wave per (b,h,qtile), S^T = K Q^T, O^T = V^T P^T, no barriers, 2.3KB LDS.

typedef unsigned short u16;
typedef float f32x4 __attribute__((ext_vector_type(4)));
typedef short s16x8 __attribute__((ext_vector_type(8)));

static constexpr int BB = 128;
static constexpr int TT = 256;
static constexpr int CC = 384;
static constexpr int HH = 6;
static constexpr int DD = 64;
static constexpr int MM = BB * TT;  // 32768

// ws layout (u16 elements): Q [M,C] | K [M,C] | VT [B,H,D,T] | WT x3 [C,C]
static constexpr size_t QOFF  = 0;
static constexpr size_t KOFF  = (size_t)MM * CC;
static constexpr size_t VOFF  = (size_t)2 * MM * CC;
static constexpr size_t WTOFF = (size_t)3 * MM * CC;

// (1/sqrt(384)) * log2(e): folded into Wq so attn logits are already base-2
static constexpr float CSC = 0.07362242194579907f;

__device__ __forceinline__ u16 f2bf(float f) {
  unsigned u = __float_as_uint(f);
  u += 0x7fffu + ((u >> 16) & 1u);   // RTN-even
  return (u16)(u >> 16);
}

// ---------- W transpose + fp32->bf16 (Wq scaled by CSC) ----------
__global__ void wtrans(const float* __restrict__ Wq, const float* __restrict__ Wk,
                       const float* __restrict__ Wv, u16* __restrict__ ws) {
  const float* W = (blockIdx.y == 0) ? Wq : (blockIdx.y == 1) ? Wk : Wv;
  const float sc = (blockIdx.y == 0) ? CSC : 1.0f;
  u16* WT = ws + WTOFF + (size_t)blockIdx.y * CC * CC;
  int i = blockIdx.x * 256 + threadIdx.x;
  int k = i / CC, n = i % CC;
  WT[(size_t)n * CC + k] = f2bf(W[i] * sc);
}

// ---------- QKV projection: 128x128 tile, BK=64, 4 waves of 64x64 ----------
__global__ __launch_bounds__(256) void gemm_qkv(const float* __restrict__ X,
                                                u16* __restrict__ ws) {
  const u16* WT = ws + WTOFF + (size_t)blockIdx.z * CC * CC;

  __shared__ u16 As[128][72];
  __shared__ u16 Bs[128][72];

  const int tid = threadIdx.x;
  const int lane = tid & 63;
  const int w = tid >> 6;
  const int quad = lane >> 4;
  const int col = lane & 15;
  const int m0 = blockIdx.x * 128;
  const int n0 = blockIdx.y * 128;
  const int wm = (w >> 1) * 64;
  const int wn = (w & 1) * 64;

  f32x4 acc[4][4] = {};

  for (int kt = 0; kt < 6; ++kt) {
    if (kt) __syncthreads();
#pragma unroll
    for (int i = 0; i < 4; ++i) {
      int c = i * 256 + tid;
      int row = c >> 3, c8 = (c & 7) * 8;
      f32x4 a0 = *(const f32x4*)(X + (size_t)(m0 + row) * CC + kt * 64 + c8);
      f32x4 a1 = *(const f32x4*)(X + (size_t)(m0 + row) * CC + kt * 64 + c8 + 4);
      s16x8 ab;
#pragma unroll
      for (int j = 0; j < 4; ++j) { ab[j] = (short)f2bf(a0[j]); ab[4 + j] = (short)f2bf(a1[j]); }
      *(s16x8*)(&As[row][c8]) = ab;
      *(uint4*)(&Bs[row][c8]) =
          *(const uint4*)(WT + (size_t)(n0 + row) * CC + kt * 64 + c8);
    }
    __syncthreads();

    s16x8 af[4][2], bf[4][2];
#pragma unroll
    for (int mt = 0; mt < 4; ++mt)
#pragma unroll
      for (int ks = 0; ks < 2; ++ks)
        af[mt][ks] = *(const s16x8*)(&As[wm + mt * 16 + col][ks * 32 + quad * 8]);
#pragma unroll
    for (int nt = 0; nt < 4; ++nt)
#pragma unroll
      for (int ks = 0; ks < 2; ++ks)
        bf[nt][ks] = *(const s16x8*)(&Bs[wn + nt * 16 + col][ks * 32 + quad * 8]);

#pragma unroll
    for (int ks = 0; ks < 2; ++ks)
#pragma unroll
      for (int mt = 0; mt < 4; ++mt)
#pragma unroll
        for (int nt = 0; nt < 4; ++nt)
          acc[mt][nt] = __builtin_amdgcn_mfma_f32_16x16x32_bf16(
              af[mt][ks], bf[nt][ks], acc[mt][nt], 0, 0, 0);
  }

  if (blockIdx.z == 2) {
    // V^T epilogue: [b][h][d][t]; rows are tokens (quad*4+r consecutive) -> 8B packed
#pragma unroll
    for (int mt = 0; mt < 4; ++mt)
#pragma unroll
      for (int nt = 0; nt < 4; ++nt) {
        int tok = m0 + wm + mt * 16 + quad * 4;
        int bb = tok >> 8, t = tok & 255;
        int ng = n0 + wn + nt * 16 + col;
        int hh = ng >> 6, d = ng & 63;
        uint2 pk;
        pk.x = (unsigned)f2bf(acc[mt][nt][0]) | ((unsigned)f2bf(acc[mt][nt][1]) << 16);
        pk.y = (unsigned)f2bf(acc[mt][nt][2]) | ((unsigned)f2bf(acc[mt][nt][3]) << 16);
        *(uint2*)(ws + VOFF + (((size_t)(bb * HH + hh) * DD + d) * TT + t)) = pk;
      }
  } else {
    u16* Y = ws + (size_t)blockIdx.z * MM * CC;
#pragma unroll
    for (int mt = 0; mt < 4; ++mt)
#pragma unroll
      for (int nt = 0; nt < 4; ++nt) {
        int mg = m0 + wm + mt * 16 + quad * 4;
        int ng = n0 + wn + nt * 16 + col;
#pragma unroll
        for (int r = 0; r < 4; ++r)
          Y[(size_t)(mg + r) * CC + ng] = f2bf(acc[mt][nt][r]);
      }
  }
}

// ---------- Flash attention: 1 wave per (b,h,qtile); S^T = K Q^T; O^T = V^T P^T ----------
__global__ __launch_bounds__(64) void attn(const u16* __restrict__ ws,
                                           float* __restrict__ out) {
  const int qt = blockIdx.x & 3;
  const int bh = blockIdx.x >> 2;
  const int b = bh / HH;
  const int h = bh % HH;

  __shared__ u16 Ps[16][72];   // P^T round-trip: [q][key], 2.3 KB

  const int lane = threadIdx.x;
  const int quad = lane >> 4;
  const int col = lane & 15;

  const u16* Qg = ws + QOFF;
  const u16* Kg = ws + KOFF;
  const u16* VTg = ws + VOFF;

  f32x4 o[4][4] = {};          // O^T acc: [mt(q16)][dt(d16)]
  float mst[4], lst[4];
#pragma unroll
  for (int mt = 0; mt < 4; ++mt) { mst[mt] = -1.0e30f; lst[mt] = 0.0f; }

  for (int kt = 0; kt <= qt; ++kt) {
    // K A-frags: lane holds K[key = nt*16+col][d = ks*32+quad*8+j]
    s16x8 kf[4][2], vf[4][2];
#pragma unroll
    for (int nt = 0; nt < 4; ++nt)
#pragma unroll
      for (int ks = 0; ks < 2; ++ks)
        kf[nt][ks] = *(const s16x8*)(Kg + (size_t)(b * TT + kt * 64 + nt * 16 + col) * CC +
                                     h * DD + ks * 32 + quad * 8);
    // V^T A-frags: lane holds V^T[d = dt*16+col][key = ks*32+quad*8+j]
#pragma unroll
    for (int dt = 0; dt < 4; ++dt)
#pragma unroll
      for (int ks = 0; ks < 2; ++ks)
        vf[dt][ks] = *(const s16x8*)(VTg + ((size_t)(bh * DD + dt * 16 + col) * TT +
                                     kt * 64 + ks * 32 + quad * 8));

#pragma unroll
    for (int mt = 0; mt < 4; ++mt) {
      // Q B-frags (pre-scaled by CSC in wtrans): [n=q=col][k=d]
      s16x8 qf[2];
#pragma unroll
      for (int ks = 0; ks < 2; ++ks)
        qf[ks] = *(const s16x8*)(Qg + (size_t)(b * TT + qt * 64 + mt * 16 + col) * CC +
                                 h * DD + ks * 32 + quad * 8);

      // S^T tiles: row = key = nt*16+quad*4+r, col = q
      f32x4 s[4] = {};
#pragma unroll
      for (int ks = 0; ks < 2; ++ks)
#pragma unroll
        for (int nt = 0; nt < 4; ++nt)
          s[nt] = __builtin_amdgcn_mfma_f32_16x16x32_bf16(kf[nt][ks], qf[ks], s[nt], 0, 0, 0);

      // causal mask (diagonal kt only) + per-lane max over this lane's 16 keys
      float rmax = -1.0e30f;
#pragma unroll
      for (int nt = 0; nt < 4; ++nt)
#pragma unroll
        for (int r = 0; r < 4; ++r) {
          float t = s[nt][r];
          if (kt == qt && (nt * 16 + quad * 4 + r) > (mt * 16 + col)) t = -1.0e30f;
          s[nt][r] = t;
          rmax = fmaxf(rmax, t);
        }
      // full 64-key max: combine the 4 quads (same q-col lives in lanes col+16k)
      rmax = fmaxf(rmax, __shfl_xor(rmax, 16));
      rmax = fmaxf(rmax, __shfl_xor(rmax, 32));

      float mn = fmaxf(mst[mt], rmax);
      float alpha = exp2f(mst[mt] - mn);
      mst[mt] = mn;

      float lsum = 0.0f;
      unsigned pk[4][2];
#pragma unroll
      for (int nt = 0; nt < 4; ++nt) {
        float p0 = exp2f(s[nt][0] - mn), p1 = exp2f(s[nt][1] - mn);
        float p2 = exp2f(s[nt][2] - mn), p3 = exp2f(s[nt][3] - mn);
        lsum += (p0 + p1) + (p2 + p3);
        pk[nt][0] = (unsigned)f2bf(p0) | ((unsigned)f2bf(p1) << 16);
        pk[nt][1] = (unsigned)f2bf(p2) | ((unsigned)f2bf(p3) << 16);
      }
      lst[mt] = lst[mt] * alpha + lsum;

      // rescale O^T for this mt
#pragma unroll
      for (int dt = 0; dt < 4; ++dt)
#pragma unroll
        for (int r = 0; r < 4; ++r) o[mt][dt][r] *= alpha;

      // P^T -> LDS [q][key]: 4 consecutive keys per lane -> b64 writes
      asm volatile("s_waitcnt lgkmcnt(0)" ::: "memory");  // WAR vs prev mt's reads
#pragma unroll
      for (int nt = 0; nt < 4; ++nt)
        *(uint2*)(&Ps[col][nt * 16 + quad * 4]) = make_uint2(pk[nt][0], pk[nt][1]);
      asm volatile("s_waitcnt lgkmcnt(0)" ::: "memory");  // writes visible to own wave

      // P^T B-frags: [k=key=ks*32+quad*8+j][n=q=col]
      s16x8 pf[2];
#pragma unroll
      for (int ks = 0; ks < 2; ++ks)
        pf[ks] = *(const s16x8*)(&Ps[col][ks * 32 + quad * 8]);

#pragma unroll
      for (int ks = 0; ks < 2; ++ks)
#pragma unroll
        for (int dt = 0; dt < 4; ++dt)
          o[mt][dt] = __builtin_amdgcn_mfma_f32_16x16x32_bf16(vf[dt][ks], pf[ks],
                                                              o[mt][dt], 0, 0, 0);
    }
  }

  // epilogue: O^T row = d = dt*16+quad*4+r, col = q -> out[b,q,h*64+d], f32x4 stores
#pragma unroll
  for (int mt = 0; mt < 4; ++mt) {
    float l = lst[mt];
    l += __shfl_xor(l, 16);
    l += __shfl_xor(l, 32);
    float inv = 1.0f / l;
    int q = qt * 64 + mt * 16 + col;
#pragma unroll
    for (int dt = 0; dt < 4; ++dt) {
      f32x4 res;
#pragma unroll
      for (int r = 0; r < 4; ++r) res[r] = o[mt][dt][r] * inv;
      *(f32x4*)(out + (size_t)(b * TT + q) * CC + h * DD + dt * 16 + quad * 4) = res;
    }
  }
}

extern "C" void kernel_launch(void* const* d_in, const int* in_sizes, int n_in,
                              void* d_out, int out_size, void* d_ws, size_t ws_size,
                              hipStream_t stream) {
  const float* x  = (const float*)d_in[0];
  const float* wq = (const float*)d_in[1];
  const float* wk = (const float*)d_in[2];
  const float* wv = (const float*)d_in[3];
  u16* ws  = (u16*)d_ws;
  float* out = (float*)d_out;

  wtrans<<<dim3(CC * CC / 256, 3), 256, 0, stream>>>(wq, wk, wv, ws);
  gemm_qkv<<<dim3(MM / 128, CC / 128, 3), 256, 0, stream>>>(x, ws);
  attn<<<dim3(BB * HH * 4), 64, 0, stream>>>(ws, out);
}